// Round 3
// baseline (293.128 us; speedup 1.0000x reference)
//
#include <hip/hip_runtime.h>
#include <hip/hip_bf16.h>

// Problem constants (hardcoded from reference)
#define T_ 6
#define Q_ 300
#define TQ 1800
#define D_ 256
#define NH_ 8
#define DH_ 32
#define L_ 4
#define P_ 7
#define DFF_ 1024
#define NV 130560   // 6 * (128*128 + 64*64 + 32*32 + 16*16)

typedef __attribute__((ext_vector_type(8))) short bf16x8;
typedef __attribute__((ext_vector_type(4))) float f32x4;
typedef __attribute__((ext_vector_type(8))) unsigned short u16x8;

__device__ inline float bf2f(unsigned short s) {
    union { unsigned u; float f; } v; v.u = ((unsigned)s) << 16;
    return v.f;
}
__device__ inline unsigned short f2b_rn(float f) {
    __hip_bfloat16 h = __float2bfloat16(f);
    union { __hip_bfloat16 h; unsigned short u; } c; c.h = h; return c.u;
}

// ---------------------------------------------------------------------------
// Value GEMM: out[NV,256] (bf16) = A[NV,256] (fp32) @ W[256,256]^T (fp32) + bias
// Direct-to-register: NO LDS, NO barriers. 512 thr = 8 waves (2m x 4n),
// wave tile 64x64 = 4x4 frags of 16x16x32. Each lane loads its own fragment
// source (A row / W row are k-contiguous), converts fp32->bf16 in-reg.
// W is 256KB -> L2-resident; A fetched exactly once per block.
// ---------------------------------------------------------------------------
__global__ __launch_bounds__(512) void vgemm_kernel(
    const float* __restrict__ A, const float* __restrict__ W,
    const float* __restrict__ bias, unsigned short* __restrict__ out)
{
    int tid = threadIdx.x;
    int wave = tid >> 6, lane = tid & 63;
    int wm = wave >> 2, wn = wave & 3;
    int r = lane & 15, g = lane >> 4;
    int m0 = blockIdx.x * 128 + wm * 64;
    int n0 = wn * 64;

    const float* ap[4]; const float* wp[4];
#pragma unroll
    for (int i = 0; i < 4; i++) {
        ap[i] = A + (size_t)(m0 + i * 16 + r) * 256 + g * 8;
        wp[i] = W + (size_t)(n0 + i * 16 + r) * 256 + g * 8;
    }

    f32x4 acc[4][4] = {};
#pragma unroll
    for (int ks = 0; ks < 8; ks++) {
        bf16x8 af[4], bfr[4];
#pragma unroll
        for (int i = 0; i < 4; i++) {
            f32x4 lo = *(const f32x4*)(ap[i] + ks * 32);
            f32x4 hi = *(const f32x4*)(ap[i] + ks * 32 + 4);
#pragma unroll
            for (int j = 0; j < 4; j++) { af[i][j] = (short)f2b_rn(lo[j]); af[i][4 + j] = (short)f2b_rn(hi[j]); }
        }
#pragma unroll
        for (int i = 0; i < 4; i++) {
            f32x4 lo = *(const f32x4*)(wp[i] + ks * 32);
            f32x4 hi = *(const f32x4*)(wp[i] + ks * 32 + 4);
#pragma unroll
            for (int j = 0; j < 4; j++) { bfr[i][j] = (short)f2b_rn(lo[j]); bfr[i][4 + j] = (short)f2b_rn(hi[j]); }
        }
#pragma unroll
        for (int mi = 0; mi < 4; mi++)
#pragma unroll
            for (int ni = 0; ni < 4; ni++)
                acc[mi][ni] = __builtin_amdgcn_mfma_f32_16x16x32_bf16(af[mi], bfr[ni], acc[mi][ni], 0, 0, 0);
    }

#pragma unroll
    for (int ni = 0; ni < 4; ni++) {
        int col = n0 + ni * 16 + r;
        float bv = bias[col];
#pragma unroll
        for (int mi = 0; mi < 4; mi++) {
#pragma unroll
            for (int rr = 0; rr < 4; rr++) {
                int row = m0 + mi * 16 + g * 4 + rr;
                out[(size_t)row * 256 + col] = f2b_rn(acc[mi][ni][rr] + bv);
            }
        }
    }
}

// ---------------------------------------------------------------------------
// Generic GEMM: out[M,N] = (A (+A2)) @ W^T + bias, bf16 MFMA, fp32 accumulate.
// Vectorized f32x4 loads. Block 256 thr = 4 waves 2x2; wave tile 32x32.
// ---------------------------------------------------------------------------
template<int RELU, int ADD2, int OUTBF16>
__global__ __launch_bounds__(256) void gemm_kernel(
    const float* __restrict__ A, const float* __restrict__ A2,
    const float* __restrict__ W, const float* __restrict__ bias,
    void* __restrict__ outp, int M, int N, int K)
{
    int wave = threadIdx.x >> 6;
    int lane = threadIdx.x & 63;
    int wm = wave >> 1, wn = wave & 1;
    int m0 = blockIdx.x * 64 + wm * 32;
    int n0 = blockIdx.y * 64 + wn * 32;
    int r = lane & 15;   // A row / B col within 16
    int g = lane >> 4;   // k group (x8)

    f32x4 acc[2][2] = {};

    for (int kk = 0; kk < K; kk += 32) {
        int kbase = kk + g * 8;
        bf16x8 af[2], wf[2];
#pragma unroll
        for (int mi = 0; mi < 2; mi++) {
            int row = m0 + mi * 16 + r; if (row >= M) row = M - 1;
            const float* ap = A + (size_t)row * K + kbase;
            f32x4 lo = *(const f32x4*)ap, hi = *(const f32x4*)(ap + 4);
            if (ADD2) {
                const float* ap2 = A2 + (size_t)row * K + kbase;
                f32x4 lo2 = *(const f32x4*)ap2, hi2 = *(const f32x4*)(ap2 + 4);
#pragma unroll
                for (int j = 0; j < 4; j++) { af[mi][j] = (short)f2b_rn(lo[j] + lo2[j]); af[mi][4 + j] = (short)f2b_rn(hi[j] + hi2[j]); }
            } else {
#pragma unroll
                for (int j = 0; j < 4; j++) { af[mi][j] = (short)f2b_rn(lo[j]); af[mi][4 + j] = (short)f2b_rn(hi[j]); }
            }
        }
#pragma unroll
        for (int ni = 0; ni < 2; ni++) {
            int col = n0 + ni * 16 + r; if (col >= N) col = N - 1;
            const float* wpp = W + (size_t)col * K + kbase;
            f32x4 lo = *(const f32x4*)wpp, hi = *(const f32x4*)(wpp + 4);
#pragma unroll
            for (int j = 0; j < 4; j++) { wf[ni][j] = (short)f2b_rn(lo[j]); wf[ni][4 + j] = (short)f2b_rn(hi[j]); }
        }
#pragma unroll
        for (int mi = 0; mi < 2; mi++)
#pragma unroll
            for (int ni = 0; ni < 2; ni++)
                acc[mi][ni] = __builtin_amdgcn_mfma_f32_16x16x32_bf16(af[mi], wf[ni], acc[mi][ni], 0, 0, 0);
    }

    float* outf = (float*)outp;
    unsigned short* outb = (unsigned short*)outp;
#pragma unroll
    for (int mi = 0; mi < 2; mi++)
#pragma unroll
        for (int ni = 0; ni < 2; ni++) {
            int col = n0 + ni * 16 + r;
            if (col < N) {
                float bv = bias ? bias[col] : 0.f;
#pragma unroll
                for (int rr = 0; rr < 4; rr++) {
                    int row = m0 + mi * 16 + g * 4 + rr;
                    if (row < M) {
                        float v = acc[mi][ni][rr] + bv;
                        if (RELU) v = fmaxf(v, 0.f);
                        size_t idx = (size_t)row * N + col;
                        if (OUTBF16) outb[idx] = f2b_rn(v); else outf[idx] = v;
                    }
                }
            }
        }
}

// ---------------------------------------------------------------------------
// Fused Q/K/V projection. Columns 0..255 -> Q (A=tgtm+qpos), 256..511 -> K
// (A=tgtm+qpos), 512..767 -> V (A=tgtm). grid (29, 12), block 256.
// ---------------------------------------------------------------------------
__global__ __launch_bounds__(256) void qkv_kernel(
    const float* __restrict__ tgtm, const float* __restrict__ qpos,
    const float* __restrict__ Wq, const float* __restrict__ bq,
    const float* __restrict__ Wk, const float* __restrict__ bk,
    const float* __restrict__ Wv, const float* __restrict__ bv,
    float* __restrict__ qh, float* __restrict__ kh, float* __restrict__ vh)
{
    int wave = threadIdx.x >> 6;
    int lane = threadIdx.x & 63;
    int wm = wave >> 1, wn = wave & 1;
    int m0 = blockIdx.x * 64 + wm * 32;
    int n0g = blockIdx.y * 64 + wn * 32;
    int seg = n0g >> 8;          // 0:Q 1:K 2:V (wave-uniform; 32 | 256)
    int n0 = n0g & 255;
    const float* W = (seg == 0) ? Wq : (seg == 1) ? Wk : Wv;
    const float* bias = (seg == 0) ? bq : (seg == 1) ? bk : bv;
    float* out = (seg == 0) ? qh : (seg == 1) ? kh : vh;
    bool add2 = (seg < 2);
    int r = lane & 15, g = lane >> 4;

    f32x4 acc[2][2] = {};
    for (int kk = 0; kk < 256; kk += 32) {
        int kbase = kk + g * 8;
        bf16x8 af[2], wf[2];
#pragma unroll
        for (int mi = 0; mi < 2; mi++) {
            int row = m0 + mi * 16 + r; if (row >= TQ) row = TQ - 1;
            const float* ap = tgtm + (size_t)row * 256 + kbase;
            f32x4 lo = *(const f32x4*)ap, hi = *(const f32x4*)(ap + 4);
            if (add2) {
                const float* ap2 = qpos + (size_t)row * 256 + kbase;
                f32x4 lo2 = *(const f32x4*)ap2, hi2 = *(const f32x4*)(ap2 + 4);
                lo += lo2; hi += hi2;
            }
#pragma unroll
            for (int j = 0; j < 4; j++) { af[mi][j] = (short)f2b_rn(lo[j]); af[mi][4 + j] = (short)f2b_rn(hi[j]); }
        }
#pragma unroll
        for (int ni = 0; ni < 2; ni++) {
            int col = n0 + ni * 16 + r;
            const float* wpp = W + (size_t)col * 256 + kbase;
            f32x4 lo = *(const f32x4*)wpp, hi = *(const f32x4*)(wpp + 4);
#pragma unroll
            for (int j = 0; j < 4; j++) { wf[ni][j] = (short)f2b_rn(lo[j]); wf[ni][4 + j] = (short)f2b_rn(hi[j]); }
        }
#pragma unroll
        for (int mi = 0; mi < 2; mi++)
#pragma unroll
            for (int ni = 0; ni < 2; ni++)
                acc[mi][ni] = __builtin_amdgcn_mfma_f32_16x16x32_bf16(af[mi], wf[ni], acc[mi][ni], 0, 0, 0);
    }
#pragma unroll
    for (int mi = 0; mi < 2; mi++)
#pragma unroll
        for (int ni = 0; ni < 2; ni++) {
            int col = n0 + ni * 16 + r;
            float bv2 = bias[col];
#pragma unroll
            for (int rr = 0; rr < 4; rr++) {
                int row = m0 + mi * 16 + g * 4 + rr;
                if (row < TQ) out[(size_t)row * 256 + col] = acc[mi][ni][rr] + bv2;
            }
        }
}

// ---------------------------------------------------------------------------
// Fused offset+attention-logit projection. Cols 0..447 -> off, 448..671 -> att.
// grid (29, 11), block 256.
// ---------------------------------------------------------------------------
__global__ __launch_bounds__(256) void offatt_kernel(
    const float* __restrict__ query,
    const float* __restrict__ Woff, const float* __restrict__ boff,
    const float* __restrict__ Watt, const float* __restrict__ batt,
    float* __restrict__ offb, float* __restrict__ attl)
{
    int wave = threadIdx.x >> 6;
    int lane = threadIdx.x & 63;
    int wm = wave >> 1, wn = wave & 1;
    int m0 = blockIdx.x * 64 + wm * 32;
    int n0g = blockIdx.y * 64 + wn * 32;
    int seg = (n0g >= 448);
    int n0 = seg ? (n0g - 448) : n0g;
    int Nloc = seg ? 224 : 448;
    const float* W = seg ? Watt : Woff;
    const float* bias = seg ? batt : boff;
    float* out = seg ? attl : offb;
    int r = lane & 15, g = lane >> 4;

    f32x4 acc[2][2] = {};
    for (int kk = 0; kk < 256; kk += 32) {
        int kbase = kk + g * 8;
        bf16x8 af[2], wf[2];
#pragma unroll
        for (int mi = 0; mi < 2; mi++) {
            int row = m0 + mi * 16 + r; if (row >= TQ) row = TQ - 1;
            const float* ap = query + (size_t)row * 256 + kbase;
            f32x4 lo = *(const f32x4*)ap, hi = *(const f32x4*)(ap + 4);
#pragma unroll
            for (int j = 0; j < 4; j++) { af[mi][j] = (short)f2b_rn(lo[j]); af[mi][4 + j] = (short)f2b_rn(hi[j]); }
        }
#pragma unroll
        for (int ni = 0; ni < 2; ni++) {
            int col = n0 + ni * 16 + r; if (col >= Nloc) col = Nloc - 1;
            const float* wpp = W + (size_t)col * 256 + kbase;
            f32x4 lo = *(const f32x4*)wpp, hi = *(const f32x4*)(wpp + 4);
#pragma unroll
            for (int j = 0; j < 4; j++) { wf[ni][j] = (short)f2b_rn(lo[j]); wf[ni][4 + j] = (short)f2b_rn(hi[j]); }
        }
#pragma unroll
        for (int mi = 0; mi < 2; mi++)
#pragma unroll
            for (int ni = 0; ni < 2; ni++)
                acc[mi][ni] = __builtin_amdgcn_mfma_f32_16x16x32_bf16(af[mi], wf[ni], acc[mi][ni], 0, 0, 0);
    }
#pragma unroll
    for (int mi = 0; mi < 2; mi++)
#pragma unroll
        for (int ni = 0; ni < 2; ni++) {
            int col = n0 + ni * 16 + r;
            if (col < Nloc) {
                float bv2 = bias[col];
#pragma unroll
                for (int rr = 0; rr < 4; rr++) {
                    int row = m0 + mi * 16 + g * 4 + rr;
                    if (row < TQ) out[(size_t)row * Nloc + col] = acc[mi][ni][rr] + bv2;
                }
            }
        }
}

// ---------------------------------------------------------------------------
// Self-attention over T=6 frames, per (query, head). One block per q (300).
// ---------------------------------------------------------------------------
__global__ __launch_bounds__(256) void selfattn_kernel(
    const float* __restrict__ qh, const float* __restrict__ kh,
    const float* __restrict__ vh, float* __restrict__ sa)
{
    int q = blockIdx.x;
    int tid = threadIdx.x;
    __shared__ float qs[T_][D_], ks[T_][D_], vs[T_][D_];
#pragma unroll
    for (int i = 0; i < T_; i++) {
        size_t base = (size_t)(i * Q_ + q) * D_ + tid;
        qs[i][tid] = qh[base]; ks[i][tid] = kh[base]; vs[i][tid] = vh[base];
    }
    __syncthreads();

    const float scale = 0.17677669529663687f; // 1/sqrt(32)
    float lg[T_][T_];
#pragma unroll
    for (int i = 0; i < T_; i++)
#pragma unroll
        for (int j = 0; j < T_; j++) {
            float p = qs[i][tid] * ks[j][tid];
#pragma unroll
            for (int m = 16; m >= 1; m >>= 1) p += __shfl_xor(p, m, 32);
            lg[i][j] = p * scale;
        }
    float o[T_];
#pragma unroll
    for (int i = 0; i < T_; i++) {
        float mx = lg[i][0];
#pragma unroll
        for (int j = 1; j < T_; j++) mx = fmaxf(mx, lg[i][j]);
        float w[T_]; float sum = 0.f;
#pragma unroll
        for (int j = 0; j < T_; j++) { w[j] = __expf(lg[i][j] - mx); sum += w[j]; }
        float inv = 1.f / sum;
        float a = 0.f;
#pragma unroll
        for (int j = 0; j < T_; j++) a += w[j] * inv * vs[j][tid];
        o[i] = a;
    }
#pragma unroll
    for (int i = 0; i < T_; i++) sa[(size_t)(i * Q_ + q) * D_ + tid] = o[i];
}

// ---------------------------------------------------------------------------
// LayerNorm: out = LN(x1 + x2) * g + b ; optionally out2 = out + add2.
// ---------------------------------------------------------------------------
__global__ __launch_bounds__(256) void ln_kernel(
    const float* __restrict__ x1, const float* __restrict__ x2,
    const float* __restrict__ gam, const float* __restrict__ bet,
    float* __restrict__ out, const float* __restrict__ add2, float* __restrict__ out2)
{
    int row = blockIdx.x;
    int tid = threadIdx.x;
    size_t idx = (size_t)row * D_ + tid;
    float v = x1[idx] + x2[idx];
    __shared__ float red[4];
    float s = v;
#pragma unroll
    for (int m = 32; m >= 1; m >>= 1) s += __shfl_xor(s, m, 64);
    if ((tid & 63) == 0) red[tid >> 6] = s;
    __syncthreads();
    float mu = (red[0] + red[1] + red[2] + red[3]) * (1.f / 256.f);
    __syncthreads();
    float dv = v - mu;
    float s2 = dv * dv;
#pragma unroll
    for (int m = 32; m >= 1; m >>= 1) s2 += __shfl_xor(s2, m, 64);
    if ((tid & 63) == 0) red[tid >> 6] = s2;
    __syncthreads();
    float var = (red[0] + red[1] + red[2] + red[3]) * (1.f / 256.f);
    float y = dv * rsqrtf(var + 1e-5f) * gam[tid] + bet[tid];
    out[idx] = y;
    if (out2) out2[idx] = y + add2[idx];
}

// ---------------------------------------------------------------------------
// Deformable sampling + attention-weighted accumulation.
// ---------------------------------------------------------------------------
__global__ __launch_bounds__(256) void sample_kernel(
    const unsigned short* __restrict__ value, const float* __restrict__ attl,
    const float* __restrict__ off, const float* __restrict__ refp,
    const float* __restrict__ vr, float* __restrict__ out)
{
    int q = blockIdx.x;
    int tid = threadIdx.x;
    int d = tid & 31, h = tid >> 5;
    int t = q / Q_, qq = q - t * Q_;

    __shared__ float aw[NH_][28], ofx[NH_][28], ofy[NH_][28];

    float lgv = (d < 28) ? attl[(size_t)q * 224 + h * 28 + d] : -1e30f;
    float mx = lgv;
#pragma unroll
    for (int m = 16; m >= 1; m >>= 1) mx = fmaxf(mx, __shfl_xor(mx, m, 32));
    float e = (d < 28) ? __expf(lgv - mx) : 0.f;
    float s = e;
#pragma unroll
    for (int m = 16; m >= 1; m >>= 1) s += __shfl_xor(s, m, 32);
    if (d < 28) {
        aw[h][d] = e / s;
        ofx[h][d] = off[(size_t)q * 448 + h * 56 + d * 2 + 0];
        ofy[h][d] = off[(size_t)q * 448 + h * 56 + d * 2 + 1];
    }
    __syncthreads();

    const int WLs[4] = {128, 64, 32, 16};
    const int LST[4] = {0, 98304, 122880, 129024};

    float acc = 0.f;
#pragma unroll
    for (int l = 0; l < L_; l++) {
        const int Wl = WLs[l], Hl = WLs[l];
        const int lst = LST[l];
        float vrx = vr[l * 2 + 0], vry = vr[l * 2 + 1];
#pragma unroll
        for (int p = 0; p < P_; p++) {
            int f = (p < 2) ? t : (((p - 2) < t) ? (p - 2) : (p - 1));
            float rx = refp[(size_t)(f * Q_ + qq) * 2 + 0];
            float ry = refp[(size_t)(f * Q_ + qq) * 2 + 1];
            int ip = l * 7 + p;
            float x = rx * vrx * (float)Wl + ofx[h][ip] - 0.5f;
            float y = ry * vry * (float)Hl + ofy[h][ip] - 0.5f;
            float x0f = floorf(x), y0f = floorf(y);
            float fx = x - x0f, fy = y - y0f;
            int x0 = (int)x0f, y0 = (int)y0f;
            int fbase = lst + f * Hl * Wl;
            float a = aw[h][ip];
#pragma unroll
            for (int dy = 0; dy < 2; dy++) {
                int yi = y0 + dy;
                float wy = dy ? fy : 1.f - fy;
                int yc = min(max(yi, 0), Hl - 1);
                bool oky = (yi >= 0) && (yi < Hl);
#pragma unroll
                for (int dx = 0; dx < 2; dx++) {
                    int xi = x0 + dx;
                    float wx = dx ? fx : 1.f - fx;
                    int xc = min(max(xi, 0), Wl - 1);
                    bool ok = oky && (xi >= 0) && (xi < Wl);
                    float v = bf2f(value[((size_t)(fbase + yc * Wl + xc)) * D_ + h * DH_ + d]);
                    acc += a * (ok ? (wy * wx) : 0.f) * v;
                }
            }
        }
    }
    out[(size_t)q * D_ + tid] = acc;
}

// ---------------------------------------------------------------------------
extern "C" void kernel_launch(void* const* d_in, const int* in_sizes, int n_in,
                              void* d_out, int out_size, void* d_ws, size_t ws_size,
                              hipStream_t stream) {
    const float* src  = (const float*)d_in[0];
    const float* tgtm = (const float*)d_in[1];
    const float* qpos = (const float*)d_in[2];
    const float* refp = (const float*)d_in[3];
    const float* vr   = (const float*)d_in[4];   // frame-0 slice: first 8 floats
    const float* Wq = (const float*)d_in[7];  const float* bq = (const float*)d_in[8];
    const float* Wk = (const float*)d_in[9];  const float* bk = (const float*)d_in[10];
    const float* Wv = (const float*)d_in[11]; const float* bv = (const float*)d_in[12];
    const float* Wo = (const float*)d_in[13]; const float* bo = (const float*)d_in[14];
    const float* n2g = (const float*)d_in[15]; const float* n2b = (const float*)d_in[16];
    const float* Wval = (const float*)d_in[17]; const float* bval = (const float*)d_in[18];
    const float* Woff = (const float*)d_in[19]; const float* boff = (const float*)d_in[20];
    const float* Watt = (const float*)d_in[21]; const float* batt = (const float*)d_in[22];
    const float* Wout = (const float*)d_in[23]; const float* bout = (const float*)d_in[24];
    const float* n1g = (const float*)d_in[25]; const float* n1b = (const float*)d_in[26];
    const float* W1 = (const float*)d_in[27]; const float* b1 = (const float*)d_in[28];
    const float* W2 = (const float*)d_in[29]; const float* b2 = (const float*)d_in[30];
    const float* n3g = (const float*)d_in[31]; const float* n3b = (const float*)d_in[32];

    char* ws = (char*)d_ws;
    size_t o = 0;
    auto alloc = [&](size_t bytes) -> void* {
        void* p = ws + o; o += (bytes + 255) & ~(size_t)255; return p;
    };
    unsigned short* value = (unsigned short*)alloc((size_t)NV * D_ * 2);
    float* qh     = (float*)alloc((size_t)TQ * D_ * 4);
    float* kh     = (float*)alloc((size_t)TQ * D_ * 4);
    float* vh     = (float*)alloc((size_t)TQ * D_ * 4);
    float* sa_raw = (float*)alloc((size_t)TQ * D_ * 4);
    float* saproj = (float*)alloc((size_t)TQ * D_ * 4);
    float* tgt1   = (float*)alloc((size_t)TQ * D_ * 4);
    float* query  = (float*)alloc((size_t)TQ * D_ * 4);
    float* offb   = (float*)alloc((size_t)TQ * 448 * 4);
    float* attl   = (float*)alloc((size_t)TQ * 224 * 4);
    float* samp   = (float*)alloc((size_t)TQ * D_ * 4);
    float* cross  = (float*)alloc((size_t)TQ * D_ * 4);
    float* tgt2   = (float*)alloc((size_t)TQ * D_ * 4);
    float* hbuf   = (float*)alloc((size_t)TQ * DFF_ * 4);
    float* ffo    = (float*)alloc((size_t)TQ * D_ * 4);

    dim3 B(256);
    const int MT = (TQ + 63) / 64;  // 29

    // Big value projection (independent of everything else): NV x 256, bf16 out
    vgemm_kernel<<<dim3(NV / 128), dim3(512), 0, stream>>>(src, Wval, bval, value);

    // Self-attention branch
    qkv_kernel<<<dim3(MT, 12), B, 0, stream>>>(tgtm, qpos, Wq, bq, Wk, bk, Wv, bv, qh, kh, vh);
    selfattn_kernel<<<dim3(Q_), B, 0, stream>>>(qh, kh, vh, sa_raw);
    gemm_kernel<0,0,0><<<dim3(MT, 4), B, 0, stream>>>(sa_raw, nullptr, Wo, bo, saproj, TQ, D_, D_);
    ln_kernel<<<dim3(TQ), B, 0, stream>>>(tgtm, saproj, n2g, n2b, tgt1, qpos, query);

    // Deformable cross-attention
    offatt_kernel<<<dim3(MT, 11), B, 0, stream>>>(query, Woff, boff, Watt, batt, offb, attl);
    sample_kernel<<<dim3(TQ), B, 0, stream>>>(value, attl, offb, refp, vr, samp);
    gemm_kernel<0,0,0><<<dim3(MT, 4), B, 0, stream>>>(samp, nullptr, Wout, bout, cross, TQ, D_, D_);
    ln_kernel<<<dim3(TQ), B, 0, stream>>>(tgt1, cross, n1g, n1b, tgt2, nullptr, nullptr);

    // FFN
    gemm_kernel<1,0,0><<<dim3(MT, 16), B, 0, stream>>>(tgt2, nullptr, W1, b1, hbuf, TQ, DFF_, D_);
    gemm_kernel<0,0,0><<<dim3(MT, 4), B, 0, stream>>>(hbuf, nullptr, W2, b2, ffo, TQ, D_, DFF_);
    ln_kernel<<<dim3(TQ), B, 0, stream>>>(tgt2, ffo, n3g, n3b, (float*)d_out, nullptr, nullptr);
}

// Round 4
// 252.450 us; speedup vs baseline: 1.1611x; 1.1611x over previous
//
#include <hip/hip_runtime.h>
#include <hip/hip_bf16.h>

// Problem constants (hardcoded from reference)
#define T_ 6
#define Q_ 300
#define TQ 1800
#define D_ 256
#define NH_ 8
#define DH_ 32
#define L_ 4
#define P_ 7
#define DFF_ 1024
#define NV 130560   // 6 * (128*128 + 64*64 + 32*32 + 16*16)
#define NVB 1020    // NV/128 vgemm blocks
#define QKVB 174    // 29 m-tiles * 6 col-tiles of 128

typedef __attribute__((ext_vector_type(8))) short bf16x8;
typedef __attribute__((ext_vector_type(4))) float f32x4;
typedef __attribute__((ext_vector_type(8))) unsigned short u16x8;

__device__ inline float bf2f(unsigned short s) {
    union { unsigned u; float f; } v; v.u = ((unsigned)s) << 16;
    return v.f;
}
__device__ inline unsigned short f2b_rn(float f) {
    __hip_bfloat16 h = __float2bfloat16(f);
    union { __hip_bfloat16 h; unsigned short u; } c; c.h = h; return c.u;
}

// ---------------------------------------------------------------------------
// Mega kernel 1: blocks [0,1020) = value GEMM; blocks [1020,1194) = QKV proj.
//
// vgemm: out[NV,256](bf16) = A[NV,256](f32) @ W[256,256]^T + bias.
//   BM=128, BN=256 (A fetched once). 512 thr = 8 waves (2m x 4n), wave 64x64.
//   Reg-staged fp32->bf16, LDS rows padded to 40 shorts (bank-conflict-free),
//   depth-2 register prefetch, RAW s_barrier + lgkmcnt(0) only (prefetch
//   loads survive the barrier; __syncthreads would drain vmcnt(0)).
// ---------------------------------------------------------------------------
__global__ __launch_bounds__(512) void mega1_kernel(
    const float* __restrict__ A, const float* __restrict__ W,
    const float* __restrict__ bias, unsigned short* __restrict__ out,
    const float* __restrict__ tgtm, const float* __restrict__ qpos,
    const float* __restrict__ Wq, const float* __restrict__ bq,
    const float* __restrict__ Wk, const float* __restrict__ bk,
    const float* __restrict__ Wv, const float* __restrict__ bv,
    float* __restrict__ qh, float* __restrict__ kh, float* __restrict__ vh)
{
    __shared__ unsigned short As[2][128 * 40];   // 20 KB
    __shared__ unsigned short Bs[2][256 * 40];   // 40 KB

    int tid = threadIdx.x;
    int wave = tid >> 6, lane = tid & 63;
    int r = lane & 15, g = lane >> 4;

    if (blockIdx.x < NVB) {
        // ------------------- value GEMM -------------------
        int wm = wave >> 2, wn = wave & 3;
        int m0 = blockIdx.x * 128;

        int arow = tid >> 2, aq = tid & 3;
        const float* aptr = A + (size_t)(m0 + arow) * 256 + aq * 8;
        int bcol = tid >> 1, bh = tid & 1;
        const float* bptr = W + (size_t)bcol * 256 + bh * 16;

        f32x4 A0a, A1a, B0a, B1a, B2a, B3a;
        f32x4 A0b, A1b, B0b, B1b, B2b, B3b;
        f32x4 acc[4][4] = {};

#define ISSUE_SET(A0, A1, B0, B1, B2, B3, kk) do { \
            A0 = *(const f32x4*)(aptr + (kk)); \
            A1 = *(const f32x4*)(aptr + (kk) + 4); \
            B0 = *(const f32x4*)(bptr + (kk)); \
            B1 = *(const f32x4*)(bptr + (kk) + 4); \
            B2 = *(const f32x4*)(bptr + (kk) + 8); \
            B3 = *(const f32x4*)(bptr + (kk) + 12); \
        } while (0)

#define KSTEP(BUF, A0, A1, B0, B1, B2, B3, ...) do { \
            u16x8 av, bv0, bv1; \
            _Pragma("unroll") \
            for (int j = 0; j < 4; j++) { \
                av[j] = f2b_rn(A0[j]); av[4 + j] = f2b_rn(A1[j]); \
                bv0[j] = f2b_rn(B0[j]); bv0[4 + j] = f2b_rn(B1[j]); \
                bv1[j] = f2b_rn(B2[j]); bv1[4 + j] = f2b_rn(B3[j]); \
            } \
            *(u16x8*)&As[BUF][arow * 40 + aq * 8] = av; \
            *(u16x8*)&Bs[BUF][bcol * 40 + bh * 16] = bv0; \
            *(u16x8*)&Bs[BUF][bcol * 40 + bh * 16 + 8] = bv1; \
            asm volatile("s_waitcnt lgkmcnt(0)" ::: "memory"); \
            __builtin_amdgcn_s_barrier(); \
            __builtin_amdgcn_sched_barrier(0); \
            __VA_ARGS__; \
            bf16x8 af[4], bfr[4]; \
            _Pragma("unroll") \
            for (int mi = 0; mi < 4; mi++) \
                af[mi] = *(const bf16x8*)&As[BUF][(wm * 64 + mi * 16 + r) * 40 + g * 8]; \
            _Pragma("unroll") \
            for (int ni = 0; ni < 4; ni++) \
                bfr[ni] = *(const bf16x8*)&Bs[BUF][(wn * 64 + ni * 16 + r) * 40 + g * 8]; \
            _Pragma("unroll") \
            for (int mi = 0; mi < 4; mi++) \
                _Pragma("unroll") \
                for (int ni = 0; ni < 4; ni++) \
                    acc[mi][ni] = __builtin_amdgcn_mfma_f32_16x16x32_bf16(af[mi], bfr[ni], acc[mi][ni], 0, 0, 0); \
        } while (0)

        ISSUE_SET(A0a, A1a, B0a, B1a, B2a, B3a, 0);
        ISSUE_SET(A0b, A1b, B0b, B1b, B2b, B3b, 32);
        KSTEP(0, A0a, A1a, B0a, B1a, B2a, B3a, ISSUE_SET(A0a, A1a, B0a, B1a, B2a, B3a, 64));
        KSTEP(1, A0b, A1b, B0b, B1b, B2b, B3b, ISSUE_SET(A0b, A1b, B0b, B1b, B2b, B3b, 96));
        KSTEP(0, A0a, A1a, B0a, B1a, B2a, B3a, ISSUE_SET(A0a, A1a, B0a, B1a, B2a, B3a, 128));
        KSTEP(1, A0b, A1b, B0b, B1b, B2b, B3b, ISSUE_SET(A0b, A1b, B0b, B1b, B2b, B3b, 160));
        KSTEP(0, A0a, A1a, B0a, B1a, B2a, B3a, ISSUE_SET(A0a, A1a, B0a, B1a, B2a, B3a, 192));
        KSTEP(1, A0b, A1b, B0b, B1b, B2b, B3b, ISSUE_SET(A0b, A1b, B0b, B1b, B2b, B3b, 224));
        KSTEP(0, A0a, A1a, B0a, B1a, B2a, B3a, );
        KSTEP(1, A0b, A1b, B0b, B1b, B2b, B3b, );
#undef KSTEP
#undef ISSUE_SET

#pragma unroll
        for (int ni = 0; ni < 4; ni++) {
            int col = wn * 64 + ni * 16 + r;
            float bv = bias[col];
#pragma unroll
            for (int mi = 0; mi < 4; mi++) {
#pragma unroll
                for (int rr = 0; rr < 4; rr++) {
                    int row = m0 + wm * 64 + mi * 16 + g * 4 + rr;
                    out[(size_t)row * 256 + col] = f2b_rn(acc[mi][ni][rr] + bv);
                }
            }
        }
    } else {
        // ------------------- fused QKV projection -------------------
        int b = blockIdx.x - NVB;
        int bmx = b % 29, by = b / 29;           // 29 m-tiles x 6 col-tiles
        int wm = wave >> 2, wn = wave & 3;       // 2m x 4n of 32x32 wave tiles
        int m0 = bmx * 64 + wm * 32;
        int n0g = by * 128 + wn * 32;            // virtual col in [0,768)
        int seg = n0g >> 8;                      // 0:Q 1:K 2:V (block-uniform)
        int n0 = n0g & 255;
        const float* Wp = (seg == 0) ? Wq : (seg == 1) ? Wk : Wv;
        const float* bp = (seg == 0) ? bq : (seg == 1) ? bk : bv;
        float* outp = (seg == 0) ? qh : (seg == 1) ? kh : vh;
        bool add2 = (seg < 2);

        f32x4 acc[2][2] = {};
#pragma unroll
        for (int kk = 0; kk < 256; kk += 32) {
            int kbase = kk + g * 8;
            bf16x8 af[2], wf[2];
#pragma unroll
            for (int mi = 0; mi < 2; mi++) {
                int row = m0 + mi * 16 + r; if (row >= TQ) row = TQ - 1;
                const float* ap = tgtm + (size_t)row * 256 + kbase;
                f32x4 lo = *(const f32x4*)ap, hi = *(const f32x4*)(ap + 4);
                if (add2) {
                    const float* ap2 = qpos + (size_t)row * 256 + kbase;
                    lo += *(const f32x4*)ap2; hi += *(const f32x4*)(ap2 + 4);
                }
#pragma unroll
                for (int j = 0; j < 4; j++) { af[mi][j] = (short)f2b_rn(lo[j]); af[mi][4 + j] = (short)f2b_rn(hi[j]); }
            }
#pragma unroll
            for (int ni = 0; ni < 2; ni++) {
                int col = n0 + ni * 16 + r;
                const float* wpp = Wp + (size_t)col * 256 + kbase;
                f32x4 lo = *(const f32x4*)wpp, hi = *(const f32x4*)(wpp + 4);
#pragma unroll
                for (int j = 0; j < 4; j++) { wf[ni][j] = (short)f2b_rn(lo[j]); wf[ni][4 + j] = (short)f2b_rn(hi[j]); }
            }
#pragma unroll
            for (int mi = 0; mi < 2; mi++)
#pragma unroll
                for (int ni = 0; ni < 2; ni++)
                    acc[mi][ni] = __builtin_amdgcn_mfma_f32_16x16x32_bf16(af[mi], wf[ni], acc[mi][ni], 0, 0, 0);
        }
#pragma unroll
        for (int mi = 0; mi < 2; mi++)
#pragma unroll
            for (int ni = 0; ni < 2; ni++) {
                int col = n0 + ni * 16 + r;
                float bv2 = bp[col];
#pragma unroll
                for (int rr = 0; rr < 4; rr++) {
                    int row = m0 + mi * 16 + g * 4 + rr;
                    if (row < TQ) outp[(size_t)row * 256 + col] = acc[mi][ni][rr] + bv2;
                }
            }
    }
}

// ---------------------------------------------------------------------------
// GEMM(+bias) + residual + LayerNorm, block owns 32 rows x full N=256.
// out = LN(res + A@W^T + bias)*g+b ; optional out2 = out + add2.
// 256 thr = 4 waves, wave = 32 rows x 64 cols (2m x 4n frags of 16x16).
// ---------------------------------------------------------------------------
template<int KDIM, int HASOUT2>
__global__ __launch_bounds__(256) void gemm_ln_kernel(
    const float* __restrict__ A, const float* __restrict__ W,
    const float* __restrict__ bias, const float* __restrict__ res,
    const float* __restrict__ gam, const float* __restrict__ bet,
    float* __restrict__ out, const float* __restrict__ add2,
    float* __restrict__ out2)
{
    __shared__ float lds[32][264];
    int tid = threadIdx.x;
    int wn = tid >> 6, lane = tid & 63;
    int r = lane & 15, g = lane >> 4;
    int m0 = blockIdx.x * 32;

    f32x4 acc[2][4] = {};
    for (int kk = 0; kk < KDIM; kk += 32) {
        int kbase = kk + g * 8;
        bf16x8 af[2], wf[4];
#pragma unroll
        for (int mi = 0; mi < 2; mi++) {
            int row = m0 + mi * 16 + r; if (row >= TQ) row = TQ - 1;
            const float* ap = A + (size_t)row * KDIM + kbase;
            f32x4 lo = *(const f32x4*)ap, hi = *(const f32x4*)(ap + 4);
#pragma unroll
            for (int j = 0; j < 4; j++) { af[mi][j] = (short)f2b_rn(lo[j]); af[mi][4 + j] = (short)f2b_rn(hi[j]); }
        }
#pragma unroll
        for (int ni = 0; ni < 4; ni++) {
            int col = wn * 64 + ni * 16 + r;
            const float* wpp = W + (size_t)col * KDIM + kbase;
            f32x4 lo = *(const f32x4*)wpp, hi = *(const f32x4*)(wpp + 4);
#pragma unroll
            for (int j = 0; j < 4; j++) { wf[ni][j] = (short)f2b_rn(lo[j]); wf[ni][4 + j] = (short)f2b_rn(hi[j]); }
        }
#pragma unroll
        for (int mi = 0; mi < 2; mi++)
#pragma unroll
            for (int ni = 0; ni < 4; ni++)
                acc[mi][ni] = __builtin_amdgcn_mfma_f32_16x16x32_bf16(af[mi], wf[ni], acc[mi][ni], 0, 0, 0);
    }

    // deposit (gemm + bias + residual) into LDS
#pragma unroll
    for (int mi = 0; mi < 2; mi++)
#pragma unroll
        for (int ni = 0; ni < 4; ni++) {
            int col = wn * 64 + ni * 16 + r;
            float bv = bias[col];
#pragma unroll
            for (int rr = 0; rr < 4; rr++) {
                int rl = mi * 16 + g * 4 + rr;
                int row = m0 + rl;
                float rv = (row < TQ) ? res[(size_t)row * 256 + col] : 0.f;
                lds[rl][col] = acc[mi][ni][rr] + bv + rv;
            }
        }
    __syncthreads();

    // LayerNorm: 8 lanes per row
    int rl = tid >> 3, l8 = tid & 7;
    float s = 0.f, s2 = 0.f;
#pragma unroll
    for (int c = 0; c < 256; c += 8) {
        float v = lds[rl][c + l8];
        s += v; s2 += v * v;
    }
#pragma unroll
    for (int m = 4; m >= 1; m >>= 1) { s += __shfl_xor(s, m, 64); s2 += __shfl_xor(s2, m, 64); }
    float mu = s * (1.f / 256.f);
    float var = s2 * (1.f / 256.f) - mu * mu;
    float rs = rsqrtf(var + 1e-5f);
    int row = m0 + rl;
    if (row < TQ) {
#pragma unroll
        for (int c = 0; c < 256; c += 8) {
            int cc = c + l8;
            float y = (lds[rl][cc] - mu) * rs * gam[cc] + bet[cc];
            out[(size_t)row * 256 + cc] = y;
            if (HASOUT2) out2[(size_t)row * 256 + cc] = y + add2[(size_t)row * 256 + cc];
        }
    }
}

// ---------------------------------------------------------------------------
// Generic GEMM (kept for FFN1): out = A@W^T + bias, optional ReLU, fp32 out.
// ---------------------------------------------------------------------------
template<int RELU>
__global__ __launch_bounds__(256) void gemm_kernel(
    const float* __restrict__ A, const float* __restrict__ W,
    const float* __restrict__ bias, float* __restrict__ outp,
    int M, int N, int K)
{
    int wave = threadIdx.x >> 6;
    int lane = threadIdx.x & 63;
    int wm = wave >> 1, wn = wave & 1;
    int m0 = blockIdx.x * 64 + wm * 32;
    int n0 = blockIdx.y * 64 + wn * 32;
    int r = lane & 15, g = lane >> 4;

    f32x4 acc[2][2] = {};
    for (int kk = 0; kk < K; kk += 32) {
        int kbase = kk + g * 8;
        bf16x8 af[2], wf[2];
#pragma unroll
        for (int mi = 0; mi < 2; mi++) {
            int row = m0 + mi * 16 + r; if (row >= M) row = M - 1;
            const float* ap = A + (size_t)row * K + kbase;
            f32x4 lo = *(const f32x4*)ap, hi = *(const f32x4*)(ap + 4);
#pragma unroll
            for (int j = 0; j < 4; j++) { af[mi][j] = (short)f2b_rn(lo[j]); af[mi][4 + j] = (short)f2b_rn(hi[j]); }
        }
#pragma unroll
        for (int ni = 0; ni < 2; ni++) {
            int col = n0 + ni * 16 + r; if (col >= N) col = N - 1;
            const float* wpp = W + (size_t)col * K + kbase;
            f32x4 lo = *(const f32x4*)wpp, hi = *(const f32x4*)(wpp + 4);
#pragma unroll
            for (int j = 0; j < 4; j++) { wf[ni][j] = (short)f2b_rn(lo[j]); wf[ni][4 + j] = (short)f2b_rn(hi[j]); }
        }
#pragma unroll
        for (int mi = 0; mi < 2; mi++)
#pragma unroll
            for (int ni = 0; ni < 2; ni++)
                acc[mi][ni] = __builtin_amdgcn_mfma_f32_16x16x32_bf16(af[mi], wf[ni], acc[mi][ni], 0, 0, 0);
    }

#pragma unroll
    for (int mi = 0; mi < 2; mi++)
#pragma unroll
        for (int ni = 0; ni < 2; ni++) {
            int col = n0 + ni * 16 + r;
            if (col < N) {
                float bv = bias[col];
#pragma unroll
                for (int rr = 0; rr < 4; rr++) {
                    int row = m0 + mi * 16 + g * 4 + rr;
                    if (row < M) {
                        float v = acc[mi][ni][rr] + bv;
                        if (RELU) v = fmaxf(v, 0.f);
                        outp[(size_t)row * N + col] = v;
                    }
                }
            }
        }
}

// ---------------------------------------------------------------------------
// Fused offset+attention-logit projection. Cols 0..447 -> off, 448..671 -> att.
// ---------------------------------------------------------------------------
__global__ __launch_bounds__(256) void offatt_kernel(
    const float* __restrict__ query,
    const float* __restrict__ Woff, const float* __restrict__ boff,
    const float* __restrict__ Watt, const float* __restrict__ batt,
    float* __restrict__ offb, float* __restrict__ attl)
{
    int wave = threadIdx.x >> 6;
    int lane = threadIdx.x & 63;
    int wm = wave >> 1, wn = wave & 1;
    int m0 = blockIdx.x * 64 + wm * 32;
    int n0g = blockIdx.y * 64 + wn * 32;
    int seg = (n0g >= 448);
    int n0 = seg ? (n0g - 448) : n0g;
    int Nloc = seg ? 224 : 448;
    const float* W = seg ? Watt : Woff;
    const float* bias = seg ? batt : boff;
    float* out = seg ? attl : offb;
    int r = lane & 15, g = lane >> 4;

    f32x4 acc[2][2] = {};
#pragma unroll
    for (int kk = 0; kk < 256; kk += 32) {
        int kbase = kk + g * 8;
        bf16x8 af[2], wf[2];
#pragma unroll
        for (int mi = 0; mi < 2; mi++) {
            int row = m0 + mi * 16 + r; if (row >= TQ) row = TQ - 1;
            const float* ap = query + (size_t)row * 256 + kbase;
            f32x4 lo = *(const f32x4*)ap, hi = *(const f32x4*)(ap + 4);
#pragma unroll
            for (int j = 0; j < 4; j++) { af[mi][j] = (short)f2b_rn(lo[j]); af[mi][4 + j] = (short)f2b_rn(hi[j]); }
        }
#pragma unroll
        for (int ni = 0; ni < 2; ni++) {
            int col = n0 + ni * 16 + r; if (col >= Nloc) col = Nloc - 1;
            const float* wpp = W + (size_t)col * 256 + kbase;
            f32x4 lo = *(const f32x4*)wpp, hi = *(const f32x4*)(wpp + 4);
#pragma unroll
            for (int j = 0; j < 4; j++) { wf[ni][j] = (short)f2b_rn(lo[j]); wf[ni][4 + j] = (short)f2b_rn(hi[j]); }
        }
#pragma unroll
        for (int mi = 0; mi < 2; mi++)
#pragma unroll
            for (int ni = 0; ni < 2; ni++)
                acc[mi][ni] = __builtin_amdgcn_mfma_f32_16x16x32_bf16(af[mi], wf[ni], acc[mi][ni], 0, 0, 0);
    }
#pragma unroll
    for (int mi = 0; mi < 2; mi++)
#pragma unroll
        for (int ni = 0; ni < 2; ni++) {
            int col = n0 + ni * 16 + r;
            if (col < Nloc) {
                float bv2 = bias[col];
#pragma unroll
                for (int rr = 0; rr < 4; rr++) {
                    int row = m0 + mi * 16 + g * 4 + rr;
                    if (row < TQ) out[(size_t)row * Nloc + col] = acc[mi][ni][rr] + bv2;
                }
            }
        }
}

// ---------------------------------------------------------------------------
// Self-attention over T=6 frames, per (query, head). One block per q (300).
// ---------------------------------------------------------------------------
__global__ __launch_bounds__(256) void selfattn_kernel(
    const float* __restrict__ qh, const float* __restrict__ kh,
    const float* __restrict__ vh, float* __restrict__ sa)
{
    int q = blockIdx.x;
    int tid = threadIdx.x;
    __shared__ float qs[T_][D_], ks[T_][D_], vs[T_][D_];
#pragma unroll
    for (int i = 0; i < T_; i++) {
        size_t base = (size_t)(i * Q_ + q) * D_ + tid;
        qs[i][tid] = qh[base]; ks[i][tid] = kh[base]; vs[i][tid] = vh[base];
    }
    __syncthreads();

    const float scale = 0.17677669529663687f; // 1/sqrt(32)
    float lg[T_][T_];
#pragma unroll
    for (int i = 0; i < T_; i++)
#pragma unroll
        for (int j = 0; j < T_; j++) {
            float p = qs[i][tid] * ks[j][tid];
#pragma unroll
            for (int m = 16; m >= 1; m >>= 1) p += __shfl_xor(p, m, 32);
            lg[i][j] = p * scale;
        }
    float o[T_];
#pragma unroll
    for (int i = 0; i < T_; i++) {
        float mx = lg[i][0];
#pragma unroll
        for (int j = 1; j < T_; j++) mx = fmaxf(mx, lg[i][j]);
        float w[T_]; float sum = 0.f;
#pragma unroll
        for (int j = 0; j < T_; j++) { w[j] = __expf(lg[i][j] - mx); sum += w[j]; }
        float inv = 1.f / sum;
        float a = 0.f;
#pragma unroll
        for (int j = 0; j < T_; j++) a += w[j] * inv * vs[j][tid];
        o[i] = a;
    }
#pragma unroll
    for (int i = 0; i < T_; i++) sa[(size_t)(i * Q_ + q) * D_ + tid] = o[i];
}

// ---------------------------------------------------------------------------
// Deformable sampling + attention-weighted accumulation.
// ---------------------------------------------------------------------------
__global__ __launch_bounds__(256) void sample_kernel(
    const unsigned short* __restrict__ value, const float* __restrict__ attl,
    const float* __restrict__ off, const float* __restrict__ refp,
    const float* __restrict__ vr, float* __restrict__ out)
{
    int q = blockIdx.x;
    int tid = threadIdx.x;
    int d = tid & 31, h = tid >> 5;
    int t = q / Q_, qq = q - t * Q_;

    __shared__ float aw[NH_][28], ofx[NH_][28], ofy[NH_][28];

    float lgv = (d < 28) ? attl[(size_t)q * 224 + h * 28 + d] : -1e30f;
    float mx = lgv;
#pragma unroll
    for (int m = 16; m >= 1; m >>= 1) mx = fmaxf(mx, __shfl_xor(mx, m, 32));
    float e = (d < 28) ? __expf(lgv - mx) : 0.f;
    float s = e;
#pragma unroll
    for (int m = 16; m >= 1; m >>= 1) s += __shfl_xor(s, m, 32);
    if (d < 28) {
        aw[h][d] = e / s;
        ofx[h][d] = off[(size_t)q * 448 + h * 56 + d * 2 + 0];
        ofy[h][d] = off[(size_t)q * 448 + h * 56 + d * 2 + 1];
    }
    __syncthreads();

    const int WLs[4] = {128, 64, 32, 16};
    const int LST[4] = {0, 98304, 122880, 129024};

    float acc = 0.f;
#pragma unroll
    for (int l = 0; l < L_; l++) {
        const int Wl = WLs[l], Hl = WLs[l];
        const int lst = LST[l];
        float vrx = vr[l * 2 + 0], vry = vr[l * 2 + 1];
#pragma unroll
        for (int p = 0; p < P_; p++) {
            int f = (p < 2) ? t : (((p - 2) < t) ? (p - 2) : (p - 1));
            float rx = refp[(size_t)(f * Q_ + qq) * 2 + 0];
            float ry = refp[(size_t)(f * Q_ + qq) * 2 + 1];
            int ip = l * 7 + p;
            float x = rx * vrx * (float)Wl + ofx[h][ip] - 0.5f;
            float y = ry * vry * (float)Hl + ofy[h][ip] - 0.5f;
            float x0f = floorf(x), y0f = floorf(y);
            float fx = x - x0f, fy = y - y0f;
            int x0 = (int)x0f, y0 = (int)y0f;
            int fbase = lst + f * Hl * Wl;
            float a = aw[h][ip];
#pragma unroll
            for (int dy = 0; dy < 2; dy++) {
                int yi = y0 + dy;
                float wy = dy ? fy : 1.f - fy;
                int yc = min(max(yi, 0), Hl - 1);
                bool oky = (yi >= 0) && (yi < Hl);
#pragma unroll
                for (int dx = 0; dx < 2; dx++) {
                    int xi = x0 + dx;
                    float wx = dx ? fx : 1.f - fx;
                    int xc = min(max(xi, 0), Wl - 1);
                    bool ok = oky && (xi >= 0) && (xi < Wl);
                    float v = bf2f(value[((size_t)(fbase + yc * Wl + xc)) * D_ + h * DH_ + d]);
                    acc += a * (ok ? (wy * wx) : 0.f) * v;
                }
            }
        }
    }
    out[(size_t)q * D_ + tid] = acc;
}

// ---------------------------------------------------------------------------
extern "C" void kernel_launch(void* const* d_in, const int* in_sizes, int n_in,
                              void* d_out, int out_size, void* d_ws, size_t ws_size,
                              hipStream_t stream) {
    const float* src  = (const float*)d_in[0];
    const float* tgtm = (const float*)d_in[1];
    const float* qpos = (const float*)d_in[2];
    const float* refp = (const float*)d_in[3];
    const float* vr   = (const float*)d_in[4];   // frame-0 slice: first 8 floats
    const float* Wq = (const float*)d_in[7];  const float* bq = (const float*)d_in[8];
    const float* Wk = (const float*)d_in[9];  const float* bk = (const float*)d_in[10];
    const float* Wv = (const float*)d_in[11]; const float* bv = (const float*)d_in[12];
    const float* Wo = (const float*)d_in[13]; const float* bo = (const float*)d_in[14];
    const float* n2g = (const float*)d_in[15]; const float* n2b = (const float*)d_in[16];
    const float* Wval = (const float*)d_in[17]; const float* bval = (const float*)d_in[18];
    const float* Woff = (const float*)d_in[19]; const float* boff = (const float*)d_in[20];
    const float* Watt = (const float*)d_in[21]; const float* batt = (const float*)d_in[22];
    const float* Wout = (const float*)d_in[23]; const float* bout = (const float*)d_in[24];
    const float* n1g = (const float*)d_in[25]; const float* n1b = (const float*)d_in[26];
    const float* W1 = (const float*)d_in[27]; const float* b1 = (const float*)d_in[28];
    const float* W2 = (const float*)d_in[29]; const float* b2 = (const float*)d_in[30];
    const float* n3g = (const float*)d_in[31]; const float* n3b = (const float*)d_in[32];

    char* ws = (char*)d_ws;
    size_t o = 0;
    auto alloc = [&](size_t bytes) -> void* {
        void* p = ws + o; o += (bytes + 255) & ~(size_t)255; return p;
    };
    unsigned short* value = (unsigned short*)alloc((size_t)NV * D_ * 2);
    float* qh     = (float*)alloc((size_t)TQ * D_ * 4);
    float* kh     = (float*)alloc((size_t)TQ * D_ * 4);
    float* vh     = (float*)alloc((size_t)TQ * D_ * 4);
    float* sa_raw = (float*)alloc((size_t)TQ * D_ * 4);
    float* tgt1   = (float*)alloc((size_t)TQ * D_ * 4);
    float* query  = (float*)alloc((size_t)TQ * D_ * 4);
    float* offb   = (float*)alloc((size_t)TQ * 448 * 4);
    float* attl   = (float*)alloc((size_t)TQ * 224 * 4);
    float* samp   = (float*)alloc((size_t)TQ * D_ * 4);
    float* tgt2   = (float*)alloc((size_t)TQ * D_ * 4);
    float* hbuf   = (float*)alloc((size_t)TQ * DFF_ * 4);

    const int MT = (TQ + 63) / 64;   // 29
    const int MLN = (TQ + 31) / 32;  // 57

    // 1) value GEMM + QKV projection in one dispatch
    mega1_kernel<<<dim3(NVB + QKVB), dim3(512), 0, stream>>>(
        src, Wval, bval, value,
        tgtm, qpos, Wq, bq, Wk, bk, Wv, bv, qh, kh, vh);

    // 2) self-attention
    selfattn_kernel<<<dim3(Q_), dim3(256), 0, stream>>>(qh, kh, vh, sa_raw);

    // 3) Wo projection + LN2 (+ query = tgt1 + qpos)
    gemm_ln_kernel<256, 1><<<dim3(MLN), dim3(256), 0, stream>>>(
        sa_raw, Wo, bo, tgtm, n2g, n2b, tgt1, qpos, query);

    // 4) offset + attention logits
    offatt_kernel<<<dim3(MT, 11), dim3(256), 0, stream>>>(query, Woff, boff, Watt, batt, offb, attl);

    // 5) deformable sampling
    sample_kernel<<<dim3(TQ), dim3(256), 0, stream>>>(value, attl, offb, refp, vr, samp);

    // 6) Wout projection + LN1
    gemm_ln_kernel<256, 0><<<dim3(MLN), dim3(256), 0, stream>>>(
        samp, Wout, bout, tgt1, n1g, n1b, tgt2, nullptr, nullptr);

    // 7) FFN1 (ReLU)
    gemm_kernel<1><<<dim3(MT, 16), dim3(256), 0, stream>>>(tgt2, W1, b1, hbuf, TQ, DFF_, D_);

    // 8) FFN2 + LN3 -> d_out
    gemm_ln_kernel<1024, 0><<<dim3(MLN), dim3(256), 0, stream>>>(
        hbuf, W2, b2, tgt2, n3g, n3b, (float*)d_out, nullptr, nullptr);
}

// Round 5
// 178.732 us; speedup vs baseline: 1.6400x; 1.4125x over previous
//
#include <hip/hip_runtime.h>
#include <hip/hip_bf16.h>

// Problem constants
#define T_ 6
#define Q_ 300
#define TQ 1800
#define D_ 256
#define NH_ 8
#define DH_ 32
#define L_ 4
#define P_ 7
#define DFF_ 1024
#define NV 130560   // 6 * (128*128 + 64*64 + 32*32 + 16*16)
#define NVB 1020    // NV/128 vgemm blocks
#define QKVB 174    // 29 m-tiles * 6 col-tiles of 128

// bf16 weight buffer offsets (elements)
#define OW_VAL 0
#define OW_Q   65536
#define OW_K   131072
#define OW_V   196608
#define OW_O   262144
#define OW_OUT 327680
#define OW_OFF 393216
#define OW_ATT 507904
#define OW_1   565248
#define OW_2   827392
#define OW_TOT 1089536

typedef __attribute__((ext_vector_type(8))) short bf16x8;
typedef __attribute__((ext_vector_type(4))) float f32x4;
typedef __attribute__((ext_vector_type(8))) unsigned short u16x8;
typedef __attribute__((ext_vector_type(4))) unsigned short u16x4;

__device__ inline float bf2f(unsigned short s) {
    union { unsigned u; float f; } v; v.u = ((unsigned)s) << 16;
    return v.f;
}
__device__ inline unsigned short f2b_rn(float f) {
    __hip_bfloat16 h = __float2bfloat16(f);
    union { __hip_bfloat16 h; unsigned short u; } c; c.h = h; return c.u;
}

// ---------------------------------------------------------------------------
// Weight conversion: 10 fp32 matrices -> one contiguous bf16 buffer.
// ---------------------------------------------------------------------------
__global__ __launch_bounds__(256) void wcvt_kernel(
    const float* __restrict__ s0, const float* __restrict__ s1,
    const float* __restrict__ s2, const float* __restrict__ s3,
    const float* __restrict__ s4, const float* __restrict__ s5,
    const float* __restrict__ s6, const float* __restrict__ s7,
    const float* __restrict__ s8, const float* __restrict__ s9,
    unsigned short* __restrict__ dst)
{
    int idx4 = blockIdx.x * blockDim.x + threadIdx.x;
    const int total4 = OW_TOT / 4;
    for (; idx4 < total4; idx4 += gridDim.x * blockDim.x) {
        int e = idx4 * 4;
        const float* s; int off;
        if      (e < OW_Q)   { s = s0; off = e; }
        else if (e < OW_K)   { s = s1; off = e - OW_Q; }
        else if (e < OW_V)   { s = s2; off = e - OW_K; }
        else if (e < OW_O)   { s = s3; off = e - OW_V; }
        else if (e < OW_OUT) { s = s4; off = e - OW_O; }
        else if (e < OW_OFF) { s = s5; off = e - OW_OUT; }
        else if (e < OW_ATT) { s = s6; off = e - OW_OFF; }
        else if (e < OW_1)   { s = s7; off = e - OW_ATT; }
        else if (e < OW_2)   { s = s8; off = e - OW_1; }
        else                 { s = s9; off = e - OW_2; }
        f32x4 v = *(const f32x4*)(s + off);
        u16x4 o;
#pragma unroll
        for (int j = 0; j < 4; j++) o[j] = f2b_rn(v[j]);
        *(u16x4*)(dst + e) = o;
    }
}

// ---------------------------------------------------------------------------
// Mega kernel: blocks [0,1020) = value GEMM; [1020,1194) = QKV projection.
// vgemm: BM=128 BN=256, 8 waves (2m x 4n), wave 64x64. B (bf16 weights) via
// global_load_lds DMA double-buffered; A reg-staged fp32->bf16 depth-1.
// Raw s_barrier + lgkmcnt(0) (prefetch survives barrier). 48KB LDS,
// forced <=128 regs -> 2 blocks/CU.
// ---------------------------------------------------------------------------
__global__ __launch_bounds__(512, 4) void mega1_kernel(
    const float* __restrict__ A, const unsigned short* __restrict__ wbf,
    const float* __restrict__ bias,
    unsigned short* __restrict__ out,
    const float* __restrict__ tgtm, const float* __restrict__ qpos,
    const float* __restrict__ bq, const float* __restrict__ bk,
    const float* __restrict__ bv,
    float* __restrict__ qh, float* __restrict__ kh, float* __restrict__ vh)
{
    __shared__ unsigned short As[2][128 * 32];   // 16 KB
    __shared__ unsigned short Bs[2][256 * 32];   // 32 KB

    int tid = threadIdx.x;
    int wave = tid >> 6, lane = tid & 63;
    int r = lane & 15, g = lane >> 4;

    if (blockIdx.x < NVB) {
        const unsigned short* Wv = wbf + OW_VAL;
        int wm = wave >> 2, wn = wave & 3;
        int m0 = blockIdx.x * 128;

        int arow = tid >> 2, aq = tid & 3;
        const float* aptr = A + (size_t)(m0 + arow) * 256 + aq * 8;

        // DMA lane-source mapping: op o writes LDS shorts
        // [(wave*2+o)*512 + lane*8 .. +8) = col ((wave*2+o)*16 + lane>>2), kk=(lane&3)*8
        int dcol = (wave * 2) * 16 + (lane >> 2);
        int dkk = (lane & 3) * 8;

        f32x4 acc[4][4] = {};
        f32x4 aLo, aHi;

#define DMA_B(ks, buf) do { \
            const unsigned short* s0_ = Wv + (size_t)dcol * 256 + (ks) * 32 + dkk; \
            const unsigned short* s1_ = s0_ + 16 * 256; \
            __builtin_amdgcn_global_load_lds( \
                (const __attribute__((address_space(1))) void*)s0_, \
                (__attribute__((address_space(3))) void*)&Bs[buf][(wave * 2 + 0) * 512], 16, 0, 0); \
            __builtin_amdgcn_global_load_lds( \
                (const __attribute__((address_space(1))) void*)s1_, \
                (__attribute__((address_space(3))) void*)&Bs[buf][(wave * 2 + 1) * 512], 16, 0, 0); \
        } while (0)

        // prologue: stage step 0
        DMA_B(0, 0);
        aLo = *(const f32x4*)(aptr);
        aHi = *(const f32x4*)(aptr + 4);

#pragma unroll
        for (int ks = 0; ks < 8; ks++) {
            const int buf = ks & 1;
            // cvt A(ks): compiler vmcnt wait here also drains DMA(ks) (issued earlier)
            u16x8 av;
#pragma unroll
            for (int j = 0; j < 4; j++) { av[j] = f2b_rn(aLo[j]); av[4 + j] = f2b_rn(aHi[j]); }
            *(u16x8*)&As[buf][arow * 32 + aq * 8] = av;

            asm volatile("s_waitcnt lgkmcnt(0)" ::: "memory");
            __builtin_amdgcn_s_barrier();
            __builtin_amdgcn_sched_barrier(0);

            // prefetch next step (post-barrier: prior readers of buf^1 are drained)
            if (ks < 7) {
                DMA_B(ks + 1, buf ^ 1);
                aLo = *(const f32x4*)(aptr + (ks + 1) * 32);
                aHi = *(const f32x4*)(aptr + (ks + 1) * 32 + 4);
            }

            bf16x8 af[4], bfr[4];
#pragma unroll
            for (int mi = 0; mi < 4; mi++)
                af[mi] = *(const bf16x8*)&As[buf][(wm * 64 + mi * 16 + r) * 32 + g * 8];
#pragma unroll
            for (int ni = 0; ni < 4; ni++)
                bfr[ni] = *(const bf16x8*)&Bs[buf][(wn * 64 + ni * 16 + r) * 32 + g * 8];
#pragma unroll
            for (int mi = 0; mi < 4; mi++)
#pragma unroll
                for (int ni = 0; ni < 4; ni++)
                    acc[mi][ni] = __builtin_amdgcn_mfma_f32_16x16x32_bf16(af[mi], bfr[ni], acc[mi][ni], 0, 0, 0);
        }
#undef DMA_B

#pragma unroll
        for (int ni = 0; ni < 4; ni++) {
            int col = wn * 64 + ni * 16 + r;
            float bv2 = bias[col];
#pragma unroll
            for (int mi = 0; mi < 4; mi++) {
#pragma unroll
                for (int rr = 0; rr < 4; rr++) {
                    int row = m0 + wm * 64 + mi * 16 + g * 4 + rr;
                    out[(size_t)row * 256 + col] = f2b_rn(acc[mi][ni][rr] + bv2);
                }
            }
        }
    } else {
        // ------------------- fused QKV projection (bf16 weights) ------------
        int b = blockIdx.x - NVB;
        int bmx = b % 29, by = b / 29;
        int wm = wave >> 2, wn = wave & 3;
        int m0 = bmx * 64 + wm * 32;
        int n0g = by * 128 + wn * 32;
        int seg = n0g >> 8;
        int n0 = n0g & 255;
        const unsigned short* Wp = wbf + (seg == 0 ? OW_Q : (seg == 1 ? OW_K : OW_V));
        const float* bp = (seg == 0) ? bq : (seg == 1) ? bk : bv;
        float* outp = (seg == 0) ? qh : (seg == 1) ? kh : vh;
        bool add2 = (seg < 2);

        f32x4 acc[2][2] = {};
#pragma unroll
        for (int kk = 0; kk < 256; kk += 32) {
            int kbase = kk + g * 8;
            bf16x8 af[2], wf[2];
#pragma unroll
            for (int mi = 0; mi < 2; mi++) {
                int row = m0 + mi * 16 + r; if (row >= TQ) row = TQ - 1;
                const float* ap = tgtm + (size_t)row * 256 + kbase;
                f32x4 lo = *(const f32x4*)ap, hi = *(const f32x4*)(ap + 4);
                if (add2) {
                    const float* ap2 = qpos + (size_t)row * 256 + kbase;
                    lo += *(const f32x4*)ap2; hi += *(const f32x4*)(ap2 + 4);
                }
#pragma unroll
                for (int j = 0; j < 4; j++) { af[mi][j] = (short)f2b_rn(lo[j]); af[mi][4 + j] = (short)f2b_rn(hi[j]); }
            }
#pragma unroll
            for (int ni = 0; ni < 2; ni++) {
                int col = n0 + ni * 16 + r;
                wf[ni] = *(const bf16x8*)&Wp[(size_t)col * 256 + kbase];
            }
#pragma unroll
            for (int mi = 0; mi < 2; mi++)
#pragma unroll
                for (int ni = 0; ni < 2; ni++)
                    acc[mi][ni] = __builtin_amdgcn_mfma_f32_16x16x32_bf16(af[mi], wf[ni], acc[mi][ni], 0, 0, 0);
        }
#pragma unroll
        for (int mi = 0; mi < 2; mi++)
#pragma unroll
            for (int ni = 0; ni < 2; ni++) {
                int col = n0 + ni * 16 + r;
                float bv2 = bp[col];
#pragma unroll
                for (int rr = 0; rr < 4; rr++) {
                    int row = m0 + mi * 16 + g * 4 + rr;
                    if (row < TQ) outp[(size_t)row * 256 + col] = acc[mi][ni][rr] + bv2;
                }
            }
    }
}

// ---------------------------------------------------------------------------
// Self-attention + Wo projection + LN2 (+ query = tgt1 + qpos).
// One block per q (300 blocks, 256 thr).
// ---------------------------------------------------------------------------
__global__ __launch_bounds__(256) void attn_wo_ln2_kernel(
    const float* __restrict__ qh, const float* __restrict__ kh,
    const float* __restrict__ vh, const float* __restrict__ tgtm,
    const float* __restrict__ qpos, const unsigned short* __restrict__ wbf,
    const float* __restrict__ bo, const float* __restrict__ n2g,
    const float* __restrict__ n2b,
    float* __restrict__ tgt1, float* __restrict__ query)
{
    int q = blockIdx.x;
    int tid = threadIdx.x;
    __shared__ float qs[T_][D_], ks_[T_][D_], vs[T_][D_];
    __shared__ unsigned short po[16][268];
    __shared__ float sa32[16][264];

#pragma unroll
    for (int i = 0; i < T_; i++) {
        size_t base = (size_t)(i * Q_ + q) * D_ + tid;
        qs[i][tid] = qh[base]; ks_[i][tid] = kh[base]; vs[i][tid] = vh[base];
    }
    __syncthreads();

    const float scale = 0.17677669529663687f; // 1/sqrt(32)
    float lg[T_][T_];
#pragma unroll
    for (int i = 0; i < T_; i++)
#pragma unroll
        for (int j = 0; j < T_; j++) {
            float p = qs[i][tid] * ks_[j][tid];
#pragma unroll
            for (int m = 16; m >= 1; m >>= 1) p += __shfl_xor(p, m, 32);
            lg[i][j] = p * scale;
        }
#pragma unroll
    for (int i = 0; i < T_; i++) {
        float mx = lg[i][0];
#pragma unroll
        for (int j = 1; j < T_; j++) mx = fmaxf(mx, lg[i][j]);
        float w[T_]; float sum = 0.f;
#pragma unroll
        for (int j = 0; j < T_; j++) { w[j] = __expf(lg[i][j] - mx); sum += w[j]; }
        float inv = 1.f / sum;
        float a = 0.f;
#pragma unroll
        for (int j = 0; j < T_; j++) a += w[j] * inv * vs[j][tid];
        po[i][tid] = f2b_rn(a);
    }
#pragma unroll
    for (int i = T_; i < 16; i++) po[i][tid] = 0;
    __syncthreads();

    // GEMM: sa16(16x256) = po @ Wo^T
    const unsigned short* Wo = wbf + OW_O;
    int wn = tid >> 6, lane = tid & 63;
    int r = lane & 15, g = lane >> 4;
    f32x4 acc[4] = {};
#pragma unroll
    for (int ksx = 0; ksx < 8; ksx++) {
        int kbase = ksx * 32 + g * 8;
        bf16x8 af = *(const bf16x8*)&po[r][kbase];
        bf16x8 bfr[4];
#pragma unroll
        for (int ni = 0; ni < 4; ni++)
            bfr[ni] = *(const bf16x8*)&Wo[(size_t)(wn * 64 + ni * 16 + r) * 256 + kbase];
#pragma unroll
        for (int ni = 0; ni < 4; ni++)
            acc[ni] = __builtin_amdgcn_mfma_f32_16x16x32_bf16(af, bfr[ni], acc[ni], 0, 0, 0);
    }
#pragma unroll
    for (int ni = 0; ni < 4; ni++) {
        int col = wn * 64 + ni * 16 + r;
#pragma unroll
        for (int rr = 0; rr < 4; rr++) {
            int row = g * 4 + rr;
            if (row < T_)
                sa32[row][col] = acc[ni][rr] + bo[col] + tgtm[(size_t)(row * Q_ + q) * 256 + col];
        }
    }
    __syncthreads();

    // LN2 rows 0..5, 8 lanes/row
    int rl = tid >> 3, l8 = tid & 7;
    if (rl < T_) {
        float s = 0.f, s2 = 0.f;
#pragma unroll
        for (int c = 0; c < 256; c += 8) {
            float v = sa32[rl][c + l8];
            s += v; s2 += v * v;
        }
#pragma unroll
        for (int m = 4; m >= 1; m >>= 1) { s += __shfl_xor(s, m, 64); s2 += __shfl_xor(s2, m, 64); }
        float mu = s * (1.f / 256.f);
        float var = s2 * (1.f / 256.f) - mu * mu;
        float rs = rsqrtf(var + 1e-5f);
        size_t grow = (size_t)(rl * Q_ + q) * 256;
#pragma unroll
        for (int c = 0; c < 256; c += 8) {
            int cc = c + l8;
            float y = (sa32[rl][cc] - mu) * rs * n2g[cc] + n2b[cc];
            tgt1[grow + cc] = y;
            query[grow + cc] = y + qpos[grow + cc];
        }
    }
}

// ---------------------------------------------------------------------------
// Fused offset+attention-logit projection (bf16 weights).
// ---------------------------------------------------------------------------
__global__ __launch_bounds__(256) void offatt_kernel(
    const float* __restrict__ query, const unsigned short* __restrict__ wbf,
    const float* __restrict__ boff, const float* __restrict__ batt,
    float* __restrict__ offb, float* __restrict__ attl)
{
    int wave = threadIdx.x >> 6;
    int lane = threadIdx.x & 63;
    int wm = wave >> 1, wn = wave & 1;
    int m0 = blockIdx.x * 64 + wm * 32;
    int n0g = blockIdx.y * 64 + wn * 32;
    int seg = (n0g >= 448);
    int n0 = seg ? (n0g - 448) : n0g;
    int Nloc = seg ? 224 : 448;
    const unsigned short* W = wbf + (seg ? OW_ATT : OW_OFF);
    const float* bias = seg ? batt : boff;
    float* out = seg ? attl : offb;
    int r = lane & 15, g = lane >> 4;

    f32x4 acc[2][2] = {};
#pragma unroll
    for (int kk = 0; kk < 256; kk += 32) {
        int kbase = kk + g * 8;
        bf16x8 af[2], wf[2];
#pragma unroll
        for (int mi = 0; mi < 2; mi++) {
            int row = m0 + mi * 16 + r; if (row >= TQ) row = TQ - 1;
            const float* ap = query + (size_t)row * 256 + kbase;
            f32x4 lo = *(const f32x4*)ap, hi = *(const f32x4*)(ap + 4);
#pragma unroll
            for (int j = 0; j < 4; j++) { af[mi][j] = (short)f2b_rn(lo[j]); af[mi][4 + j] = (short)f2b_rn(hi[j]); }
        }
#pragma unroll
        for (int ni = 0; ni < 2; ni++) {
            int col = n0 + ni * 16 + r; if (col >= Nloc) col = Nloc - 1;
            wf[ni] = *(const bf16x8*)&W[(size_t)col * 256 + kbase];
        }
#pragma unroll
        for (int mi = 0; mi < 2; mi++)
#pragma unroll
            for (int ni = 0; ni < 2; ni++)
                acc[mi][ni] = __builtin_amdgcn_mfma_f32_16x16x32_bf16(af[mi], wf[ni], acc[mi][ni], 0, 0, 0);
    }
#pragma unroll
    for (int mi = 0; mi < 2; mi++)
#pragma unroll
        for (int ni = 0; ni < 2; ni++) {
            int col = n0 + ni * 16 + r;
            if (col < Nloc) {
                float bv2 = bias[col];
#pragma unroll
                for (int rr = 0; rr < 4; rr++) {
                    int row = m0 + mi * 16 + g * 4 + rr;
                    if (row < TQ) out[(size_t)row * Nloc + col] = acc[mi][ni][rr] + bv2;
                }
            }
        }
}

// ---------------------------------------------------------------------------
// Deformable sampling + attention-weighted accumulation.
// ---------------------------------------------------------------------------
__global__ __launch_bounds__(256) void sample_kernel(
    const unsigned short* __restrict__ value, const float* __restrict__ attl,
    const float* __restrict__ off, const float* __restrict__ refp,
    const float* __restrict__ vr, float* __restrict__ out)
{
    int q = blockIdx.x;
    int tid = threadIdx.x;
    int d = tid & 31, h = tid >> 5;
    int t = q / Q_, qq = q - t * Q_;

    __shared__ float aw[NH_][28], ofx[NH_][28], ofy[NH_][28];

    float lgv = (d < 28) ? attl[(size_t)q * 224 + h * 28 + d] : -1e30f;
    float mx = lgv;
#pragma unroll
    for (int m = 16; m >= 1; m >>= 1) mx = fmaxf(mx, __shfl_xor(mx, m, 32));
    float e = (d < 28) ? __expf(lgv - mx) : 0.f;
    float s = e;
#pragma unroll
    for (int m = 16; m >= 1; m >>= 1) s += __shfl_xor(s, m, 32);
    if (d < 28) {
        aw[h][d] = e / s;
        ofx[h][d] = off[(size_t)q * 448 + h * 56 + d * 2 + 0];
        ofy[h][d] = off[(size_t)q * 448 + h * 56 + d * 2 + 1];
    }
    __syncthreads();

    const int WLs[4] = {128, 64, 32, 16};
    const int LST[4] = {0, 98304, 122880, 129024};

    float acc = 0.f;
#pragma unroll
    for (int l = 0; l < L_; l++) {
        const int Wl = WLs[l], Hl = WLs[l];
        const int lst = LST[l];
        float vrx = vr[l * 2 + 0], vry = vr[l * 2 + 1];
#pragma unroll
        for (int p = 0; p < P_; p++) {
            int f = (p < 2) ? t : (((p - 2) < t) ? (p - 2) : (p - 1));
            float rx = refp[(size_t)(f * Q_ + qq) * 2 + 0];
            float ry = refp[(size_t)(f * Q_ + qq) * 2 + 1];
            int ip = l * 7 + p;
            float x = rx * vrx * (float)Wl + ofx[h][ip] - 0.5f;
            float y = ry * vry * (float)Hl + ofy[h][ip] - 0.5f;
            float x0f = floorf(x), y0f = floorf(y);
            float fx = x - x0f, fy = y - y0f;
            int x0 = (int)x0f, y0 = (int)y0f;
            int fbase = lst + f * Hl * Wl;
            float a = aw[h][ip];
#pragma unroll
            for (int dy = 0; dy < 2; dy++) {
                int yi = y0 + dy;
                float wy = dy ? fy : 1.f - fy;
                int yc = min(max(yi, 0), Hl - 1);
                bool oky = (yi >= 0) && (yi < Hl);
#pragma unroll
                for (int dx = 0; dx < 2; dx++) {
                    int xi = x0 + dx;
                    float wx = dx ? fx : 1.f - fx;
                    int xc = min(max(xi, 0), Wl - 1);
                    bool ok = oky && (xi >= 0) && (xi < Wl);
                    float v = bf2f(value[((size_t)(fbase + yc * Wl + xc)) * D_ + h * DH_ + d]);
                    acc += a * (ok ? (wy * wx) : 0.f) * v;
                }
            }
        }
    }
    out[(size_t)q * D_ + tid] = acc;
}

// ---------------------------------------------------------------------------
// Tail: Wout+bias+res(tgt1) -> LN1 -> FFN1(relu) -> FFN2+res -> LN3 -> d_out.
// One block per 16 rows (113 blocks, 256 thr). All intermediates in LDS.
// ---------------------------------------------------------------------------
__global__ __launch_bounds__(256) void tail_kernel(
    const float* __restrict__ samp, const unsigned short* __restrict__ wbf,
    const float* __restrict__ bout, const float* __restrict__ tgt1,
    const float* __restrict__ n1g, const float* __restrict__ n1b,
    const float* __restrict__ b1, const float* __restrict__ b2,
    const float* __restrict__ n3g, const float* __restrict__ n3b,
    float* __restrict__ dout)
{
    __shared__ float c32[16][264];
    __shared__ float t232[16][264];
    __shared__ unsigned short t2bf[16][268];
    __shared__ unsigned short hbf[16][1036];

    int tid = threadIdx.x;
    int wn = tid >> 6, lane = tid & 63;
    int r = lane & 15, g = lane >> 4;
    int m0 = blockIdx.x * 16;

    const unsigned short* Wout = wbf + OW_OUT;
    const unsigned short* W1 = wbf + OW_1;
    const unsigned short* W2 = wbf + OW_2;

    // ---- Phase A: cross = samp @ Wout^T ----
    {
        f32x4 acc[4] = {};
        int row = m0 + r; if (row >= TQ) row = TQ - 1;
#pragma unroll
        for (int ksx = 0; ksx < 8; ksx++) {
            int kbase = ksx * 32 + g * 8;
            const float* ap = samp + (size_t)row * 256 + kbase;
            f32x4 lo = *(const f32x4*)ap, hi = *(const f32x4*)(ap + 4);
            bf16x8 af;
#pragma unroll
            for (int j = 0; j < 4; j++) { af[j] = (short)f2b_rn(lo[j]); af[4 + j] = (short)f2b_rn(hi[j]); }
            bf16x8 bfr[4];
#pragma unroll
            for (int ni = 0; ni < 4; ni++)
                bfr[ni] = *(const bf16x8*)&Wout[(size_t)(wn * 64 + ni * 16 + r) * 256 + kbase];
#pragma unroll
            for (int ni = 0; ni < 4; ni++)
                acc[ni] = __builtin_amdgcn_mfma_f32_16x16x32_bf16(af, bfr[ni], acc[ni], 0, 0, 0);
        }
#pragma unroll
        for (int ni = 0; ni < 4; ni++) {
            int col = wn * 64 + ni * 16 + r;
            float bv = bout[col];
#pragma unroll
            for (int rr = 0; rr < 4; rr++) {
                int rowl = g * 4 + rr;
                int grow = m0 + rowl;
                float res = (grow < TQ) ? tgt1[(size_t)grow * 256 + col] : 0.f;
                c32[rowl][col] = acc[ni][rr] + bv + res;
            }
        }
    }
    __syncthreads();

    // ---- LN1 -> t232 (fp32) and t2bf (bf16) ----
    if (tid < 128) {
        int rl = tid >> 3, l8 = tid & 7;
        float s = 0.f, s2 = 0.f;
#pragma unroll
        for (int c = 0; c < 256; c += 8) {
            float v = c32[rl][c + l8];
            s += v; s2 += v * v;
        }
#pragma unroll
        for (int m = 4; m >= 1; m >>= 1) { s += __shfl_xor(s, m, 64); s2 += __shfl_xor(s2, m, 64); }
        float mu = s * (1.f / 256.f);
        float var = s2 * (1.f / 256.f) - mu * mu;
        float rs = rsqrtf(var + 1e-5f);
#pragma unroll
        for (int c = 0; c < 256; c += 8) {
            int cc = c + l8;
            float y = (c32[rl][cc] - mu) * rs * n1g[cc] + n1b[cc];
            t232[rl][cc] = y;
            t2bf[rl][cc] = f2b_rn(y);
        }
    }
    __syncthreads();

    // ---- Phase B: h = relu(t2 @ W1^T + b1), cols wn*256..+255 ----
    {
        f32x4 acc[16] = {};
#pragma unroll
        for (int ksx = 0; ksx < 8; ksx++) {
            int kbase = ksx * 32 + g * 8;
            bf16x8 af = *(const bf16x8*)&t2bf[r][kbase];
#pragma unroll
            for (int ni = 0; ni < 16; ni++) {
                bf16x8 bfr = *(const bf16x8*)&W1[(size_t)(wn * 256 + ni * 16 + r) * 256 + kbase];
                acc[ni] = __builtin_amdgcn_mfma_f32_16x16x32_bf16(af, bfr, acc[ni], 0, 0, 0);
            }
        }
#pragma unroll
        for (int ni = 0; ni < 16; ni++) {
            int col = wn * 256 + ni * 16 + r;
            float bv = b1[col];
#pragma unroll
            for (int rr = 0; rr < 4; rr++) {
                int rowl = g * 4 + rr;
                hbf[rowl][col] = f2b_rn(fmaxf(acc[ni][rr] + bv, 0.f));
            }
        }
    }
    __syncthreads();

    // ---- Phase C: f = h @ W2^T + b2 + t2 ----
    {
        f32x4 acc[4] = {};
#pragma unroll
        for (int ksx = 0; ksx < 32; ksx++) {
            int kbase = ksx * 32 + g * 8;
            bf16x8 af = *(const bf16x8*)&hbf[r][kbase];
#pragma unroll
            for (int ni = 0; ni < 4; ni++) {
                bf16x8 bfr = *(const bf16x8*)&W2[(size_t)(wn * 64 + ni * 16 + r) * 1024 + kbase];
                acc[ni] = __builtin_amdgcn_mfma_f32_16x16x32_bf16(af, bfr, acc[ni], 0, 0, 0);
            }
        }
#pragma unroll
        for (int ni = 0; ni < 4; ni++) {
            int col = wn * 64 + ni * 16 + r;
            float bv = b2[col];
#pragma unroll
            for (int rr = 0; rr < 4; rr++) {
                int rowl = g * 4 + rr;
                c32[rowl][col] = acc[ni][rr] + bv + t232[rowl][col];
            }
        }
    }
    __syncthreads();

    // ---- LN3 -> d_out ----
    if (tid < 128) {
        int rl = tid >> 3, l8 = tid & 7;
        int grow = m0 + rl;
        if (grow < TQ) {
            float s = 0.f, s2 = 0.f;
#pragma unroll
            for (int c = 0; c < 256; c += 8) {
                float v = c32[rl][c + l8];
                s += v; s2 += v * v;
            }
#pragma unroll
            for (int m = 4; m >= 1; m >>= 1) { s += __shfl_xor(s, m, 64); s2 += __shfl_xor(s2, m, 64); }
            float mu = s * (1.f / 256.f);
            float var = s2 * (1.f / 256.f) - mu * mu;
            float rs = rsqrtf(var + 1e-5f);
#pragma unroll
            for (int c = 0; c < 256; c += 8) {
                int cc = c + l8;
                dout[(size_t)grow * 256 + cc] = (c32[rl][cc] - mu) * rs * n3g[cc] + n3b[cc];
            }
        }
    }
}

// ---------------------------------------------------------------------------
extern "C" void kernel_launch(void* const* d_in, const int* in_sizes, int n_in,
                              void* d_out, int out_size, void* d_ws, size_t ws_size,
                              hipStream_t stream) {
    const float* src  = (const float*)d_in[0];
    const float* tgtm = (const float*)d_in[1];
    const float* qpos = (const float*)d_in[2];
    const float* refp = (const float*)d_in[3];
    const float* vr   = (const float*)d_in[4];   // frame-0 slice: first 8 floats
    const float* Wq = (const float*)d_in[7];  const float* bq = (const float*)d_in[8];
    const float* Wk = (const float*)d_in[9];  const float* bk = (const float*)d_in[10];
    const float* Wv = (const float*)d_in[11]; const float* bv = (const float*)d_in[12];
    const float* Wo = (const float*)d_in[13]; const float* bo = (const float*)d_in[14];
    const float* n2g = (const float*)d_in[15]; const float* n2b = (const float*)d_in[16];
    const float* Wval = (const float*)d_in[17]; const float* bval = (const float*)d_in[18];
    const float* Woff = (const float*)d_in[19]; const float* boff = (const float*)d_in[20];
    const float* Watt = (const float*)d_in[21]; const float* batt = (const float*)d_in[22];
    const float* Wout = (const float*)d_in[23]; const float* bout = (const float*)d_in[24];
    const float* n1g = (const float*)d_in[25]; const float* n1b = (const float*)d_in[26];
    const float* W1 = (const float*)d_in[27]; const float* b1 = (const float*)d_in[28];
    const float* W2 = (const float*)d_in[29]; const float* b2 = (const float*)d_in[30];
    const float* n3g = (const float*)d_in[31]; const float* n3b = (const float*)d_in[32];

    char* ws = (char*)d_ws;
    size_t o = 0;
    auto alloc = [&](size_t bytes) -> void* {
        void* p = ws + o; o += (bytes + 255) & ~(size_t)255; return p;
    };
    unsigned short* value = (unsigned short*)alloc((size_t)NV * D_ * 2);
    unsigned short* wbf   = (unsigned short*)alloc((size_t)OW_TOT * 2);
    float* qh     = (float*)alloc((size_t)TQ * D_ * 4);
    float* kh     = (float*)alloc((size_t)TQ * D_ * 4);
    float* vh     = (float*)alloc((size_t)TQ * D_ * 4);
    float* tgt1   = (float*)alloc((size_t)TQ * D_ * 4);
    float* query  = (float*)alloc((size_t)TQ * D_ * 4);
    float* offb   = (float*)alloc((size_t)TQ * 448 * 4);
    float* attl   = (float*)alloc((size_t)TQ * 224 * 4);
    float* samp   = (float*)alloc((size_t)TQ * D_ * 4);

    const int MT = (TQ + 63) / 64;   // 29

    // 0) convert all weights to bf16
    wcvt_kernel<<<dim3((OW_TOT / 4 + 255) / 256), dim3(256), 0, stream>>>(
        Wval, Wq, Wk, Wv, Wo, Wout, Woff, Watt, W1, W2, wbf);

    // 1) value GEMM + QKV projection
    mega1_kernel<<<dim3(NVB + QKVB), dim3(512), 0, stream>>>(
        src, wbf, bval, value, tgtm, qpos, bq, bk, bv, qh, kh, vh);

    // 2) self-attention + Wo + LN2 (+query)
    attn_wo_ln2_kernel<<<dim3(Q_), dim3(256), 0, stream>>>(
        qh, kh, vh, tgtm, qpos, wbf, bo, n2g, n2b, tgt1, query);

    // 3) offset + attention logits
    offatt_kernel<<<dim3(MT, 11), dim3(256), 0, stream>>>(query, wbf, boff, batt, offb, attl);

    // 4) deformable sampling
    sample_kernel<<<dim3(TQ), dim3(256), 0, stream>>>(value, attl, offb, refp, vr, samp);

    // 5) fused tail: Wout+LN1 + FFN1 + FFN2+LN3 -> d_out
    tail_kernel<<<dim3((TQ + 15) / 16), dim3(256), 0, stream>>>(
        samp, wbf, bout, tgt1, n1g, n1b, b1, b2, n3g, n3b, (float*)d_out);
}